// Round 9
// baseline (1418.466 us; speedup 1.0000x reference)
//
#include <hip/hip_runtime.h>
#include <hip/hip_bf16.h>

// Mix2Layer: out[b,o] = sum_k relu(sum_i x[b,i]*w1[i,o,k] + b1[o,k]) * (sum_i x[b,i]*w2[i,o,k]) + b2[o]
// B=2048, DIN=2048, DOUT=2048, K=16.  N' = o*16+k (w row-major [DIN][32768]).
//
// Fast path (needs ws >= 264MB):
//   1) xcvt:   x fp32 -> bf16                  (8 MB)
//   2) wtrans: w[i][n'] fp32 -> wt[n'][i] bf16 (128 MB each)
//   3) mix2_gemmv: PRODUCER-CONSUMER wave specialization (9 waves):
//      wave 8 stages all tiles (32 gload_lds/half, vmcnt(0) paced, ring-of-4);
//      waves 0-7 run pure {barrier; 12 ds_reads; 32 MFMA} phases — no vmcnt,
//      no staging on the consumer critical path. 16x16x32 MFMA (conflict-free).
// Fallback: round-1 in-kernel-transpose kernel (verified passing).

typedef __bf16 bf16;
typedef bf16 bf16x8 __attribute__((ext_vector_type(8)));
typedef bf16 bf16x4 __attribute__((ext_vector_type(4)));
typedef float f32x4 __attribute__((ext_vector_type(4)));

typedef __attribute__((address_space(1))) const void gco_void;
typedef __attribute__((address_space(3))) void lds_void;

#define DIN_   2048
#define DOUT_  2048
#define NP_    32768   // DOUT*K

__device__ __forceinline__ bf16x8 cvt8(f32x4 a, f32x4 b) {
    bf16x8 v;
    v[0] = (bf16)a[0]; v[1] = (bf16)a[1]; v[2] = (bf16)a[2]; v[3] = (bf16)a[3];
    v[4] = (bf16)b[0]; v[5] = (bf16)b[1]; v[6] = (bf16)b[2]; v[7] = (bf16)b[3];
    return v;
}

// ---------------- prep 1: x fp32 -> bf16 ----------------
__global__ __launch_bounds__(256)
void xcvt(const float* __restrict__ x, bf16* __restrict__ xb) {
    const size_t i = ((size_t)blockIdx.x * 256 + threadIdx.x) * 8;
    f32x4 a = *(const f32x4*)(x + i);
    f32x4 b = *(const f32x4*)(x + i + 4);
    *(bf16x8*)(xb + i) = cvt8(a, b);
}

// ---------------- prep 2: w[i][n'] fp32 -> wt[n'][i] bf16 ----------------
__global__ __launch_bounds__(256)
void wtrans(const float* __restrict__ w1, const float* __restrict__ w2,
            bf16* __restrict__ w1t, bf16* __restrict__ w2t) {
    __shared__ float s[64][65];
    const int t  = threadIdx.x;
    const int lr = t >> 4;      // 0..15
    const int lq = t & 15;      // 0..15
    const int n0 = blockIdx.x * 64;
    const int i0 = blockIdx.y * 64;
    const float* src = blockIdx.z ? w2 : w1;
    bf16*        dst = blockIdx.z ? w2t : w1t;
#pragma unroll
    for (int r = 0; r < 4; ++r) {
        const int il = lr + 16 * r;
        f32x4 v = *(const f32x4*)(src + (size_t)(i0 + il) * NP_ + n0 + lq * 4);
        s[il][lq * 4 + 0] = v[0]; s[il][lq * 4 + 1] = v[1];
        s[il][lq * 4 + 2] = v[2]; s[il][lq * 4 + 3] = v[3];
    }
    __syncthreads();
#pragma unroll
    for (int r = 0; r < 4; ++r) {
        const int nl = lr + 16 * r;
        bf16x4 o;
        o[0] = (bf16)s[lq * 4 + 0][nl]; o[1] = (bf16)s[lq * 4 + 1][nl];
        o[2] = (bf16)s[lq * 4 + 2][nl]; o[3] = (bf16)s[lq * 4 + 3][nl];
        *(bf16x4*)(dst + (size_t)(n0 + nl) * DIN_ + i0 + lq * 4) = o;
    }
}

// ---------------- main: producer-consumer dual-B GEMM ----------------
// Tile 256(m) x 128(n'); 64 K-halves of 32 k; ring of 4 LDS regions (32KB):
//   region r = h&3: [A 256x32k 16KB][B1 128x32k 8KB][B2 128x32k 8KB]
// rows 64B; 16B slots pre-swizzled: phys slot p of row r holds data slot
// p ^ ((r>>1)&3)  (producer lane l: slot (l&3)^((l>>3)&3), j-invariant).
// Producer (wave 8), per phase: vmcnt(0) [S(h) landed]; STGP(h+1); barrier.
// Consumers (waves 0-7), per phase: barrier; 12 ds_read_b128; 32 MFMA.
__global__ __launch_bounds__(576, 1)
void mix2_gemmv(const bf16* __restrict__ xb, const bf16* __restrict__ w1t,
                const bf16* __restrict__ w2t, const float* __restrict__ b1,
                const float* __restrict__ b2, float* __restrict__ out)
{
    __shared__ alignas(16) char lds[131072];

    const int tid  = threadIdx.x;
    const int lane = tid & 63;
    const int wid  = tid >> 6;     // 0..8

    const int nwg = gridDim.x;     // 2048
    const int bid = (blockIdx.x & 7) * (nwg >> 3) + (blockIdx.x >> 3);
    const int mt  = bid & 7;       // 8 m-tiles of 256
    const int nt  = bid >> 3;      // 256 n-panels of 128

    if (wid == 8) {
        // -------- producer wave --------
        const int lr = lane >> 2;                              // row within 16-row chunk
        const int ls = ((lane & 3) ^ ((lane >> 3) & 3)) * 8;   // pre-swizzled slot (elems)
        const bf16* pA  = xb  + (size_t)(mt * 256 + lr) * DIN_ + ls;
        const bf16* pB1 = w1t + (size_t)(nt * 128 + lr) * DIN_ + ls;
        const bf16* pB2 = w2t + (size_t)(nt * 128 + lr) * DIN_ + ls;

        auto STGP = [&](int h) {   // 32 gload_lds = full 32KB region
            char* r = lds + (h & 3) * 32768;
            const int ko = h * 32;
#pragma unroll
            for (int j = 0; j < 16; ++j)
                __builtin_amdgcn_global_load_lds((gco_void*)(pA + (size_t)j * 16 * DIN_ + ko),
                                                 (lds_void*)(r + j * 1024), 16, 0, 0);
#pragma unroll
            for (int j = 0; j < 8; ++j)
                __builtin_amdgcn_global_load_lds((gco_void*)(pB1 + (size_t)j * 16 * DIN_ + ko),
                                                 (lds_void*)(r + 16384 + j * 1024), 16, 0, 0);
#pragma unroll
            for (int j = 0; j < 8; ++j)
                __builtin_amdgcn_global_load_lds((gco_void*)(pB2 + (size_t)j * 16 * DIN_ + ko),
                                                 (lds_void*)(r + 24576 + j * 1024), 16, 0, 0);
        };

        STGP(0);
        asm volatile("s_waitcnt vmcnt(0)" ::: "memory");   // S(0) landed (<=32 outstanding rule)
        STGP(1);
        __builtin_amdgcn_s_barrier();                      // top of phase 0
#pragma unroll 1
        for (int h = 1; h <= 62; ++h) {
            asm volatile("s_waitcnt vmcnt(0)" ::: "memory");  // S(h) landed
            __builtin_amdgcn_sched_barrier(0);
            STGP(h + 1);                                      // region (h+1)&3: safe (ring-4)
            __builtin_amdgcn_s_barrier();                     // top of phase h
        }
        asm volatile("s_waitcnt vmcnt(0)" ::: "memory");      // S(63) landed
        __builtin_amdgcn_s_barrier();                         // top of phase 63
        return;                                               // no more barriers below
    }

    // -------- consumer waves (0..7) --------
    const int wm = wid >> 2;       // 0..1  (128-row slab)
    const int wn = wid & 3;        // 0..3  (32-col slab)
    const int lk = lane & 15;
    const int lg = lane >> 4;

    const int kswz = (lg ^ ((lk >> 1) & 3)) * 16;
    int aoff[8], boff[2];
#pragma unroll
    for (int fm = 0; fm < 8; ++fm) aoff[fm] = (wm * 128 + fm * 16 + lk) * 64 + kswz;
#pragma unroll
    for (int fn = 0; fn < 2; ++fn) boff[fn] = (wn * 32 + fn * 16 + lk) * 64 + kswz;

    f32x4 acc1[8][2], acc2[8][2];
#pragma unroll
    for (int i = 0; i < 8; ++i)
#pragma unroll
        for (int j = 0; j < 2; ++j) {
            acc1[i][j] = (f32x4){0.f, 0.f, 0.f, 0.f};
            acc2[i][j] = (f32x4){0.f, 0.f, 0.f, 0.f};
        }

    auto PHASE = [&](int h) {      // 12 ds_read_b128 + 32 MFMA
        const char* r = lds + (h & 3) * 32768;
        bf16x8 a[8], u[2], v[2];
#pragma unroll
        for (int fn = 0; fn < 2; ++fn) {
            u[fn] = *(const bf16x8*)(r + 16384 + boff[fn]);
            v[fn] = *(const bf16x8*)(r + 24576 + boff[fn]);
        }
#pragma unroll
        for (int fm = 0; fm < 8; ++fm) a[fm] = *(const bf16x8*)(r + aoff[fm]);
        __builtin_amdgcn_s_setprio(1);
#pragma unroll
        for (int fm = 0; fm < 8; ++fm)
#pragma unroll
            for (int fn = 0; fn < 2; ++fn) {
                acc1[fm][fn] = __builtin_amdgcn_mfma_f32_16x16x32_bf16(a[fm], u[fn], acc1[fm][fn], 0, 0, 0);
                acc2[fm][fn] = __builtin_amdgcn_mfma_f32_16x16x32_bf16(a[fm], v[fn], acc2[fm][fn], 0, 0, 0);
            }
        __builtin_amdgcn_s_setprio(0);
    };

    __builtin_amdgcn_s_barrier();            // top of phase 0 (S(0) published)
    __builtin_amdgcn_sched_barrier(0);
    PHASE(0);
#pragma unroll 1
    for (int h = 1; h < 64; ++h) {
        __builtin_amdgcn_s_barrier();        // top of phase h (S(h) published,
        __builtin_amdgcn_sched_barrier(0);   //  licenses producer overwrite)
        PHASE(h);
    }

    // ---- epilogue: k-reduce via shfl_xor, cols lane&15 = 16 k's of one o ----
    const int obase = nt * 8 + wn * 2;
#pragma unroll
    for (int fn = 0; fn < 2; ++fn) {
        const int o = obase + fn;
        const float bb1 = b1[(size_t)o * 16 + lk];
        const float bb2 = b2[o];
#pragma unroll
        for (int fm = 0; fm < 8; ++fm) {
#pragma unroll
            for (int j = 0; j < 4; ++j) {
                float g = fmaxf(acc1[fm][fn][j] + bb1, 0.f);
                float p = g * acc2[fm][fn][j];
                p += __shfl_xor(p, 1);
                p += __shfl_xor(p, 2);
                p += __shfl_xor(p, 4);
                p += __shfl_xor(p, 8);
                if (lk == 0) {
                    const int brow = mt * 256 + wm * 128 + fm * 16 + lg * 4 + j;
                    out[(size_t)brow * DOUT_ + o] = p + bb2;
                }
            }
        }
    }
}

// ---------------- fallback: round-1 kernel (verified passing) ----------------
__global__ __launch_bounds__(512)
void mix2_fused_direct(const float* __restrict__ x, const float* __restrict__ w1,
                       const float* __restrict__ b1, const float* __restrict__ w2,
                       const float* __restrict__ b2, float* __restrict__ out)
{
    __shared__ alignas(16) char lds[2 * 49152];

    const int tid  = threadIdx.x;
    const int lane = tid & 63;
    const int wid  = tid >> 6;
    const int wm   = wid >> 2;
    const int wn   = wid & 3;

    const int nwg = gridDim.x;
    const int bid = (blockIdx.x & 7) * (nwg >> 3) + (blockIdx.x >> 3);
    const int mt  = bid & 15;
    const int nt  = bid >> 4;

    const int lk  = lane & 15;
    const int lg  = lane >> 4;
    const int swz = (lane & 7) << 4;

    const int a_row  = tid >> 3;
    const int a_col8 = tid & 7;
    const int b_ib = ((tid >> 5) & 15) << 2;
    const int b_nb = (tid & 31) << 2;

    const float* pa  = x  + (size_t)(mt * 128 + a_row) * DIN_ + a_col8 * 8;
    const float* pb1 = w1 + (size_t)b_ib * NP_ + (size_t)nt * 128 + b_nb;
    const float* pb2 = w2 + (size_t)b_ib * NP_ + (size_t)nt * 128 + b_nb;

    const int aswz   = (a_col8 * 16) ^ ((a_row & 7) << 4);
    const int aoffw0 = a_row * 128 + aswz;
    const int aoffw1 = (a_row + 64) * 128 + aswz;

    int aoff[4], boff1[2], boff2[2];
#pragma unroll
    for (int fm = 0; fm < 4; ++fm) aoff[fm] = (wm * 64 + fm * 16 + lk) * 128;
#pragma unroll
    for (int fn = 0; fn < 2; ++fn) {
        const int n = wn * 32 + fn * 16 + lk;
        boff1[fn] = 16384 + n * 128;
        boff2[fn] = 32768 + n * 128;
    }
    const int kp0 = (lg * 16) ^ swz;
    const int kp1 = (64 + lg * 16) ^ swz;

    f32x4 acc1[4][2], acc2[4][2];
#pragma unroll
    for (int i = 0; i < 4; ++i)
#pragma unroll
        for (int j = 0; j < 2; ++j) {
            acc1[i][j] = (f32x4){0.f, 0.f, 0.f, 0.f};
            acc2[i][j] = (f32x4){0.f, 0.f, 0.f, 0.f};
        }

    f32x4 rA[4], rB1[4], rB2[4];

    auto LOAD = [&](int kt) {
        const float* a0 = pa + kt * 64;
        rA[0] = *(const f32x4*)(a0);
        rA[1] = *(const f32x4*)(a0 + 4);
        rA[2] = *(const f32x4*)(a0 + (size_t)64 * DIN_);
        rA[3] = *(const f32x4*)(a0 + (size_t)64 * DIN_ + 4);
        const float* q1 = pb1 + (size_t)kt * 64 * NP_;
        const float* q2 = pb2 + (size_t)kt * 64 * NP_;
#pragma unroll
        for (int j = 0; j < 4; ++j) {
            rB1[j] = *(const f32x4*)(q1 + (size_t)j * NP_);
            rB2[j] = *(const f32x4*)(q2 + (size_t)j * NP_);
        }
    };

    auto STORE = [&](char* s) {
        *(bf16x8*)(s + aoffw0) = cvt8(rA[0], rA[1]);
        *(bf16x8*)(s + aoffw1) = cvt8(rA[2], rA[3]);
        char* s1 = s + 16384;
        char* s2 = s + 32768;
#pragma unroll
        for (int c = 0; c < 4; ++c) {
            const int n   = b_nb + c;
            const int off = n * 128 + ((b_ib * 2) ^ ((n & 7) << 4));
            bf16x4 v1, v2;
            v1[0] = (bf16)rB1[0][c]; v1[1] = (bf16)rB1[1][c];
            v1[2] = (bf16)rB1[2][c]; v1[3] = (bf16)rB1[3][c];
            v2[0] = (bf16)rB2[0][c]; v2[1] = (bf16)rB2[1][c];
            v2[2] = (bf16)rB2[2][c]; v2[3] = (bf16)rB2[3][c];
            *(bf16x4*)(s1 + off) = v1;
            *(bf16x4*)(s2 + off) = v2;
        }
    };

    auto COMPUTE = [&](const char* s) {
#pragma unroll
        for (int kb = 0; kb < 2; ++kb) {
            const int kp = kb ? kp1 : kp0;
            bf16x8 a[4], u[2], v[2];
#pragma unroll
            for (int fm = 0; fm < 4; ++fm) a[fm] = *(const bf16x8*)(s + aoff[fm] + kp);
#pragma unroll
            for (int fn = 0; fn < 2; ++fn) u[fn] = *(const bf16x8*)(s + boff1[fn] + kp);
#pragma unroll
            for (int fn = 0; fn < 2; ++fn) v[fn] = *(const bf16x8*)(s + boff2[fn] + kp);
#pragma unroll
            for (int fm = 0; fm < 4; ++fm)
#pragma unroll
                for (int fn = 0; fn < 2; ++fn) {
                    acc1[fm][fn] = __builtin_amdgcn_mfma_f32_16x16x32_bf16(a[fm], u[fn], acc1[fm][fn], 0, 0, 0);
                    acc2[fm][fn] = __builtin_amdgcn_mfma_f32_16x16x32_bf16(a[fm], v[fn], acc2[fm][fn], 0, 0, 0);
                }
        }
    };

    char* buf0 = lds;
    char* buf1 = lds + 49152;

    LOAD(0);
    STORE(buf0);
    __syncthreads();

    for (int kt = 0; kt < 32; ++kt) {
        if (kt + 1 < 32) LOAD(kt + 1);
        COMPUTE((kt & 1) ? buf1 : buf0);
        if (kt + 1 < 32) {
            STORE((kt & 1) ? buf0 : buf1);
            __syncthreads();
        }
    }

    const int obase = nt * 8 + wn * 2;
#pragma unroll
    for (int fn = 0; fn < 2; ++fn) {
        const int o = obase + fn;
        const float bb1 = b1[(size_t)o * 16 + lk];
        const float bb2 = b2[o];
#pragma unroll
        for (int fm = 0; fm < 4; ++fm) {
#pragma unroll
            for (int j = 0; j < 4; ++j) {
                float g = fmaxf(acc1[fm][fn][j] + bb1, 0.f);
                float p = g * acc2[fm][fn][j];
                p += __shfl_xor(p, 1);
                p += __shfl_xor(p, 2);
                p += __shfl_xor(p, 4);
                p += __shfl_xor(p, 8);
                if (lk == 0) {
                    const int brow = mt * 128 + wm * 64 + fm * 16 + lg * 4 + j;
                    out[(size_t)brow * DOUT_ + o] = p + bb2;
                }
            }
        }
    }
}

extern "C" void kernel_launch(void* const* d_in, const int* in_sizes, int n_in,
                              void* d_out, int out_size, void* d_ws, size_t ws_size,
                              hipStream_t stream) {
    (void)in_sizes; (void)n_in; (void)out_size;
    const float* x  = (const float*)d_in[0];
    const float* w1 = (const float*)d_in[1];
    const float* b1 = (const float*)d_in[2];
    const float* w2 = (const float*)d_in[3];
    const float* b2 = (const float*)d_in[4];
    float* out = (float*)d_out;

    const size_t XB   = (size_t)DIN_ * DIN_ * 2;            // 8 MB   (x bf16)
    const size_t WT   = (size_t)NP_ * DIN_ * 2;             // 128 MB (each wt)
    const size_t NEED = XB + 2 * WT;                        // 264 MB

    if (ws_size >= NEED) {
        bf16* xb  = (bf16*)d_ws;
        bf16* w1t = (bf16*)((char*)d_ws + XB);
        bf16* w2t = (bf16*)((char*)d_ws + XB + WT);
        hipLaunchKernelGGL(xcvt,   dim3(2048),       dim3(256), 0, stream, x, xb);
        hipLaunchKernelGGL(wtrans, dim3(512, 32, 2), dim3(256), 0, stream, w1, w2, w1t, w2t);
        hipLaunchKernelGGL(mix2_gemmv, dim3(2048),   dim3(576), 0, stream, xb, w1t, w2t, b1, b2, out);
    } else {
        hipLaunchKernelGGL(mix2_fused_direct, dim3(4096), dim3(512), 0, stream, x, w1, b1, w2, b2, out);
    }
}

// Round 10
// 726.051 us; speedup vs baseline: 1.9537x; 1.9537x over previous
//
#include <hip/hip_runtime.h>
#include <hip/hip_bf16.h>

// Mix2Layer: out[b,o] = sum_k relu(sum_i x[b,i]*w1[i,o,k] + b1[o,k]) * (sum_i x[b,i]*w2[i,o,k]) + b2[o]
// B=2048, DIN=2048, DOUT=2048, K=16.  N' = o*16+k (w row-major [DIN][32768]).
//
// Fast path (needs ws >= 264MB):
//   1) xcvt:   x fp32 -> bf16                  (8 MB)
//   2) wtrans: w[i][n'] fp32 -> wt[n'][i] bf16 (128 MB each)
//   3) mix2_gemmr3: 128x128 tile, ring-of-3 (72KB LDS -> 2 blocks/CU),
//      counted vmcnt(3) per K-step (1 tile in flight), gload_lds staging w/
//      pre-swizzled source, 8 ds_reads + 16 MFMA per wave per step.
//      TLP from 2 resident blocks hides barrier/read windows.
// Fallback: round-1 in-kernel-transpose kernel (verified passing).

typedef __bf16 bf16;
typedef bf16 bf16x8 __attribute__((ext_vector_type(8)));
typedef bf16 bf16x4 __attribute__((ext_vector_type(4)));
typedef float f32x4 __attribute__((ext_vector_type(4)));

typedef __attribute__((address_space(1))) const void gco_void;
typedef __attribute__((address_space(3))) void lds_void;

#define DIN_   2048
#define DOUT_  2048
#define NP_    32768   // DOUT*K

__device__ __forceinline__ bf16x8 cvt8(f32x4 a, f32x4 b) {
    bf16x8 v;
    v[0] = (bf16)a[0]; v[1] = (bf16)a[1]; v[2] = (bf16)a[2]; v[3] = (bf16)a[3];
    v[4] = (bf16)b[0]; v[5] = (bf16)b[1]; v[6] = (bf16)b[2]; v[7] = (bf16)b[3];
    return v;
}

// ---------------- prep 1: x fp32 -> bf16 ----------------
__global__ __launch_bounds__(256)
void xcvt(const float* __restrict__ x, bf16* __restrict__ xb) {
    const size_t i = ((size_t)blockIdx.x * 256 + threadIdx.x) * 8;
    f32x4 a = *(const f32x4*)(x + i);
    f32x4 b = *(const f32x4*)(x + i + 4);
    *(bf16x8*)(xb + i) = cvt8(a, b);
}

// ---------------- prep 2: w[i][n'] fp32 -> wt[n'][i] bf16 ----------------
__global__ __launch_bounds__(256)
void wtrans(const float* __restrict__ w1, const float* __restrict__ w2,
            bf16* __restrict__ w1t, bf16* __restrict__ w2t) {
    __shared__ float s[64][65];
    const int t  = threadIdx.x;
    const int lr = t >> 4;      // 0..15
    const int lq = t & 15;      // 0..15
    const int n0 = blockIdx.x * 64;
    const int i0 = blockIdx.y * 64;
    const float* src = blockIdx.z ? w2 : w1;
    bf16*        dst = blockIdx.z ? w2t : w1t;
#pragma unroll
    for (int r = 0; r < 4; ++r) {
        const int il = lr + 16 * r;
        f32x4 v = *(const f32x4*)(src + (size_t)(i0 + il) * NP_ + n0 + lq * 4);
        s[il][lq * 4 + 0] = v[0]; s[il][lq * 4 + 1] = v[1];
        s[il][lq * 4 + 2] = v[2]; s[il][lq * 4 + 3] = v[3];
    }
    __syncthreads();
#pragma unroll
    for (int r = 0; r < 4; ++r) {
        const int nl = lr + 16 * r;
        bf16x4 o;
        o[0] = (bf16)s[lq * 4 + 0][nl]; o[1] = (bf16)s[lq * 4 + 1][nl];
        o[2] = (bf16)s[lq * 4 + 2][nl]; o[3] = (bf16)s[lq * 4 + 3][nl];
        *(bf16x4*)(dst + (size_t)(n0 + nl) * DIN_ + i0 + lq * 4) = o;
    }
}

// ---------------- main: 128x128 ring-of-3, 2 blocks/CU ----------------
// 64 K-steps of 32 k; ring of 3 LDS regions (24KB):
//   region r = kt%3: [A 128x32k 8KB][B1 128x32k 8KB][B2 128x32k 8KB]
// rows 64B; 16B slots pre-swizzled: phys slot p of row r holds slot p^((r>>1)&3).
// Per step kt: vmcnt(3) [S(kt) landed; S(kt+1) 3 loads in flight]; barrier;
// STG(kt+2) -> region (kt-1)%3 (reads done before this barrier);
// 8 ds_read_b128 + 16 MFMA (compiler-counted lgkm), setprio around MFMA.
__global__ __launch_bounds__(512, 4)
void mix2_gemmr3(const bf16* __restrict__ xb, const bf16* __restrict__ w1t,
                 const bf16* __restrict__ w2t, const float* __restrict__ b1,
                 const float* __restrict__ b2, float* __restrict__ out)
{
    __shared__ alignas(16) char lds[73728];   // 3 x 24KB

    const int tid  = threadIdx.x;
    const int lane = tid & 63;
    const int wid  = tid >> 6;
    const int wm   = wid >> 2;     // 0..1 (64-row slab)
    const int wn   = wid & 3;      // 0..3 (32-col slab)
    const int lk   = lane & 15;
    const int lg   = lane >> 4;

    const int nwg = gridDim.x;     // 4096
    const int bid = (blockIdx.x & 7) * (nwg >> 3) + (blockIdx.x >> 3);
    const int mt  = bid & 15;      // 16 m-tiles of 128
    const int nt  = bid >> 4;      // 256 n-panels of 128

    // staging: thread t -> row = t>>2 (0..127), phys slot = t&3; src pre-swizzled
    const int srow = tid >> 2;
    const int sswz = ((tid & 3) ^ ((srow >> 1) & 3)) * 8;
    const bf16* gA  = xb  + (size_t)(mt * 128 + srow) * DIN_ + sswz;
    const bf16* gB1 = w1t + (size_t)(nt * 128 + srow) * DIN_ + sswz;
    const bf16* gB2 = w2t + (size_t)(nt * 128 + srow) * DIN_ + sswz;

    const int kswz = (lg ^ ((lk >> 1) & 3)) * 16;
    int aoff[4], boff[2];
#pragma unroll
    for (int fm = 0; fm < 4; ++fm) aoff[fm] = (wm * 64 + fm * 16 + lk) * 64 + kswz;
#pragma unroll
    for (int fn = 0; fn < 2; ++fn) boff[fn] = (wn * 32 + fn * 16 + lk) * 64 + kswz;

    f32x4 acc1[4][2], acc2[4][2];
#pragma unroll
    for (int i = 0; i < 4; ++i)
#pragma unroll
        for (int j = 0; j < 2; ++j) {
            acc1[i][j] = (f32x4){0.f, 0.f, 0.f, 0.f};
            acc2[i][j] = (f32x4){0.f, 0.f, 0.f, 0.f};
        }

    const int ldw = wid * 1024;
    auto STG = [&](int kt, int reg) {    // 3 gload_lds into region reg
        char* r = lds + reg * 24576;
        const int c = kt * 32;
        __builtin_amdgcn_global_load_lds((gco_void*)(gA  + c), (lds_void*)(r +         ldw), 16, 0, 0);
        __builtin_amdgcn_global_load_lds((gco_void*)(gB1 + c), (lds_void*)(r +  8192 + ldw), 16, 0, 0);
        __builtin_amdgcn_global_load_lds((gco_void*)(gB2 + c), (lds_void*)(r + 16384 + ldw), 16, 0, 0);
    };

    auto PHASE = [&](int reg) {          // 8 ds_read_b128 + 16 MFMA
        const char* r = lds + reg * 24576;
        bf16x8 a[4], u[2], v[2];
#pragma unroll
        for (int fn = 0; fn < 2; ++fn) {
            u[fn] = *(const bf16x8*)(r +  8192 + boff[fn]);
            v[fn] = *(const bf16x8*)(r + 16384 + boff[fn]);
        }
#pragma unroll
        for (int fm = 0; fm < 4; ++fm) a[fm] = *(const bf16x8*)(r + aoff[fm]);
        __builtin_amdgcn_s_setprio(1);
#pragma unroll
        for (int fm = 0; fm < 4; ++fm)
#pragma unroll
            for (int fn = 0; fn < 2; ++fn) {
                acc1[fm][fn] = __builtin_amdgcn_mfma_f32_16x16x32_bf16(a[fm], u[fn], acc1[fm][fn], 0, 0, 0);
                acc2[fm][fn] = __builtin_amdgcn_mfma_f32_16x16x32_bf16(a[fm], v[fn], acc2[fm][fn], 0, 0, 0);
            }
        __builtin_amdgcn_s_setprio(0);
    };

#define STEP(kt, R, RS) do {                                    \
    asm volatile("s_waitcnt vmcnt(3)" ::: "memory");            \
    __builtin_amdgcn_s_barrier();                               \
    __builtin_amdgcn_sched_barrier(0);                          \
    STG((kt) + 2, RS);                                          \
    PHASE(R);                                                   \
} while (0)

    // prologue: stage S(0) -> region 0, S(1) -> region 1  (6 loads out)
    STG(0, 0); STG(1, 1);

    // kt = 0..59 (stages S(2)..S(61)); regions static via 3x unroll
#pragma unroll 1
    for (int t = 0; t < 20; ++t) {
        const int k0 = 3 * t;
        STEP(k0 + 0, 0, 2);
        STEP(k0 + 1, 1, 0);
        STEP(k0 + 2, 2, 1);
    }
    // kt = 60 (stage S(62) -> reg 2), 61 (stage S(63) -> reg 0)
    STEP(60, 0, 2);
    STEP(61, 1, 0);
    // kt = 62: outstanding S(62),S(63) -> wait 3 leaves S(63) in flight
    asm volatile("s_waitcnt vmcnt(3)" ::: "memory");
    __builtin_amdgcn_s_barrier();
    __builtin_amdgcn_sched_barrier(0);
    PHASE(2);
    // kt = 63
    asm volatile("s_waitcnt vmcnt(0)" ::: "memory");
    __builtin_amdgcn_s_barrier();
    __builtin_amdgcn_sched_barrier(0);
    PHASE(0);

#undef STEP

    // ---- epilogue: k-reduce via shfl_xor, cols lane&15 = 16 k's of one o ----
    const int obase = nt * 8 + wn * 2;
#pragma unroll
    for (int fn = 0; fn < 2; ++fn) {
        const int o = obase + fn;
        const float bb1 = b1[(size_t)o * 16 + lk];
        const float bb2 = b2[o];
#pragma unroll
        for (int fm = 0; fm < 4; ++fm) {
#pragma unroll
            for (int j = 0; j < 4; ++j) {
                float g = fmaxf(acc1[fm][fn][j] + bb1, 0.f);
                float p = g * acc2[fm][fn][j];
                p += __shfl_xor(p, 1);
                p += __shfl_xor(p, 2);
                p += __shfl_xor(p, 4);
                p += __shfl_xor(p, 8);
                if (lk == 0) {
                    const int brow = mt * 128 + wm * 64 + fm * 16 + lg * 4 + j;
                    out[(size_t)brow * DOUT_ + o] = p + bb2;
                }
            }
        }
    }
}

// ---------------- fallback: round-1 kernel (verified passing) ----------------
__global__ __launch_bounds__(512)
void mix2_fused_direct(const float* __restrict__ x, const float* __restrict__ w1,
                       const float* __restrict__ b1, const float* __restrict__ w2,
                       const float* __restrict__ b2, float* __restrict__ out)
{
    __shared__ alignas(16) char lds[2 * 49152];

    const int tid  = threadIdx.x;
    const int lane = tid & 63;
    const int wid  = tid >> 6;
    const int wm   = wid >> 2;
    const int wn   = wid & 3;

    const int nwg = gridDim.x;
    const int bid = (blockIdx.x & 7) * (nwg >> 3) + (blockIdx.x >> 3);
    const int mt  = bid & 15;
    const int nt  = bid >> 4;

    const int lk  = lane & 15;
    const int lg  = lane >> 4;
    const int swz = (lane & 7) << 4;

    const int a_row  = tid >> 3;
    const int a_col8 = tid & 7;
    const int b_ib = ((tid >> 5) & 15) << 2;
    const int b_nb = (tid & 31) << 2;

    const float* pa  = x  + (size_t)(mt * 128 + a_row) * DIN_ + a_col8 * 8;
    const float* pb1 = w1 + (size_t)b_ib * NP_ + (size_t)nt * 128 + b_nb;
    const float* pb2 = w2 + (size_t)b_ib * NP_ + (size_t)nt * 128 + b_nb;

    const int aswz   = (a_col8 * 16) ^ ((a_row & 7) << 4);
    const int aoffw0 = a_row * 128 + aswz;
    const int aoffw1 = (a_row + 64) * 128 + aswz;

    int aoff[4], boff1[2], boff2[2];
#pragma unroll
    for (int fm = 0; fm < 4; ++fm) aoff[fm] = (wm * 64 + fm * 16 + lk) * 128;
#pragma unroll
    for (int fn = 0; fn < 2; ++fn) {
        const int n = wn * 32 + fn * 16 + lk;
        boff1[fn] = 16384 + n * 128;
        boff2[fn] = 32768 + n * 128;
    }
    const int kp0 = (lg * 16) ^ swz;
    const int kp1 = (64 + lg * 16) ^ swz;

    f32x4 acc1[4][2], acc2[4][2];
#pragma unroll
    for (int i = 0; i < 4; ++i)
#pragma unroll
        for (int j = 0; j < 2; ++j) {
            acc1[i][j] = (f32x4){0.f, 0.f, 0.f, 0.f};
            acc2[i][j] = (f32x4){0.f, 0.f, 0.f, 0.f};
        }

    f32x4 rA[4], rB1[4], rB2[4];

    auto LOAD = [&](int kt) {
        const float* a0 = pa + kt * 64;
        rA[0] = *(const f32x4*)(a0);
        rA[1] = *(const f32x4*)(a0 + 4);
        rA[2] = *(const f32x4*)(a0 + (size_t)64 * DIN_);
        rA[3] = *(const f32x4*)(a0 + (size_t)64 * DIN_ + 4);
        const float* q1 = pb1 + (size_t)kt * 64 * NP_;
        const float* q2 = pb2 + (size_t)kt * 64 * NP_;
#pragma unroll
        for (int j = 0; j < 4; ++j) {
            rB1[j] = *(const f32x4*)(q1 + (size_t)j * NP_);
            rB2[j] = *(const f32x4*)(q2 + (size_t)j * NP_);
        }
    };

    auto STORE = [&](char* s) {
        *(bf16x8*)(s + aoffw0) = cvt8(rA[0], rA[1]);
        *(bf16x8*)(s + aoffw1) = cvt8(rA[2], rA[3]);
        char* s1 = s + 16384;
        char* s2 = s + 32768;
#pragma unroll
        for (int c = 0; c < 4; ++c) {
            const int n   = b_nb + c;
            const int off = n * 128 + ((b_ib * 2) ^ ((n & 7) << 4));
            bf16x4 v1, v2;
            v1[0] = (bf16)rB1[0][c]; v1[1] = (bf16)rB1[1][c];
            v1[2] = (bf16)rB1[2][c]; v1[3] = (bf16)rB1[3][c];
            v2[0] = (bf16)rB2[0][c]; v2[1] = (bf16)rB2[1][c];
            v2[2] = (bf16)rB2[2][c]; v2[3] = (bf16)rB2[3][c];
            *(bf16x4*)(s1 + off) = v1;
            *(bf16x4*)(s2 + off) = v2;
        }
    };

    auto COMPUTE = [&](const char* s) {
#pragma unroll
        for (int kb = 0; kb < 2; ++kb) {
            const int kp = kb ? kp1 : kp0;
            bf16x8 a[4], u[2], v[2];
#pragma unroll
            for (int fm = 0; fm < 4; ++fm) a[fm] = *(const bf16x8*)(s + aoff[fm] + kp);
#pragma unroll
            for (int fn = 0; fn < 2; ++fn) u[fn] = *(const bf16x8*)(s + boff1[fn] + kp);
#pragma unroll
            for (int fn = 0; fn < 2; ++fn) v[fn] = *(const bf16x8*)(s + boff2[fn] + kp);
#pragma unroll
            for (int fm = 0; fm < 4; ++fm)
#pragma unroll
                for (int fn = 0; fn < 2; ++fn) {
                    acc1[fm][fn] = __builtin_amdgcn_mfma_f32_16x16x32_bf16(a[fm], u[fn], acc1[fm][fn], 0, 0, 0);
                    acc2[fm][fn] = __builtin_amdgcn_mfma_f32_16x16x32_bf16(a[fm], v[fn], acc2[fm][fn], 0, 0, 0);
                }
        }
    };

    char* buf0 = lds;
    char* buf1 = lds + 49152;

    LOAD(0);
    STORE(buf0);
    __syncthreads();

    for (int kt = 0; kt < 32; ++kt) {
        if (kt + 1 < 32) LOAD(kt + 1);
        COMPUTE((kt & 1) ? buf1 : buf0);
        if (kt + 1 < 32) {
            STORE((kt & 1) ? buf0 : buf1);
            __syncthreads();
        }
    }

    const int obase = nt * 8 + wn * 2;
#pragma unroll
    for (int fn = 0; fn < 2; ++fn) {
        const int o = obase + fn;
        const float bb1 = b1[(size_t)o * 16 + lk];
        const float bb2 = b2[o];
#pragma unroll
        for (int fm = 0; fm < 4; ++fm) {
#pragma unroll
            for (int j = 0; j < 4; ++j) {
                float g = fmaxf(acc1[fm][fn][j] + bb1, 0.f);
                float p = g * acc2[fm][fn][j];
                p += __shfl_xor(p, 1);
                p += __shfl_xor(p, 2);
                p += __shfl_xor(p, 4);
                p += __shfl_xor(p, 8);
                if (lk == 0) {
                    const int brow = mt * 128 + wm * 64 + fm * 16 + lg * 4 + j;
                    out[(size_t)brow * DOUT_ + o] = p + bb2;
                }
            }
        }
    }
}

extern "C" void kernel_launch(void* const* d_in, const int* in_sizes, int n_in,
                              void* d_out, int out_size, void* d_ws, size_t ws_size,
                              hipStream_t stream) {
    (void)in_sizes; (void)n_in; (void)out_size;
    const float* x  = (const float*)d_in[0];
    const float* w1 = (const float*)d_in[1];
    const float* b1 = (const float*)d_in[2];
    const float* w2 = (const float*)d_in[3];
    const float* b2 = (const float*)d_in[4];
    float* out = (float*)d_out;

    const size_t XB   = (size_t)DIN_ * DIN_ * 2;            // 8 MB   (x bf16)
    const size_t WT   = (size_t)NP_ * DIN_ * 2;             // 128 MB (each wt)
    const size_t NEED = XB + 2 * WT;                        // 264 MB

    if (ws_size >= NEED) {
        bf16* xb  = (bf16*)d_ws;
        bf16* w1t = (bf16*)((char*)d_ws + XB);
        bf16* w2t = (bf16*)((char*)d_ws + XB + WT);
        hipLaunchKernelGGL(xcvt,   dim3(2048),       dim3(256), 0, stream, x, xb);
        hipLaunchKernelGGL(wtrans, dim3(512, 32, 2), dim3(256), 0, stream, w1, w2, w1t, w2t);
        hipLaunchKernelGGL(mix2_gemmr3, dim3(4096),  dim3(512), 0, stream, xb, w1t, w2t, b1, b2, out);
    } else {
        hipLaunchKernelGGL(mix2_fused_direct, dim3(4096), dim3(512), 0, stream, x, w1, b1, w2, b2, out);
    }
}

// Round 11
// 642.784 us; speedup vs baseline: 2.2068x; 1.1295x over previous
//
#include <hip/hip_runtime.h>
#include <hip/hip_bf16.h>

// Mix2Layer: out[b,o] = sum_k relu(sum_i x[b,i]*w1[i,o,k] + b1[o,k]) * (sum_i x[b,i]*w2[i,o,k]) + b2[o]
// B=2048, DIN=2048, DOUT=2048, K=16.  N' = o*16+k (w row-major [DIN][32768]).
//
// Fast path (needs ws >= 264MB):
//   1) xcvt:   x fp32 -> bf16                  (8 MB)
//   2) wtrans: w[i][n'] fp32 -> wt[n'][i] bf16 (128 MB each)
//   3) mix2_gemm16w: 256x128 tile, 16 waves (4 waves/SIMD), ring-of-4,
//      counted vmcnt, gload_lds w/ pre-swizzled source. 64-VGPR acc per wave
//      keeps total <=128 -> all 16 waves resident; deep wave co-scheduling
//      hides the fixed per-phase sync cost.
// Fallback: round-1 in-kernel-transpose kernel (verified passing).

typedef __bf16 bf16;
typedef bf16 bf16x8 __attribute__((ext_vector_type(8)));
typedef bf16 bf16x4 __attribute__((ext_vector_type(4)));
typedef float f32x4 __attribute__((ext_vector_type(4)));

typedef __attribute__((address_space(1))) const void gco_void;
typedef __attribute__((address_space(3))) void lds_void;

#define DIN_   2048
#define DOUT_  2048
#define NP_    32768   // DOUT*K

__device__ __forceinline__ bf16x8 cvt8(f32x4 a, f32x4 b) {
    bf16x8 v;
    v[0] = (bf16)a[0]; v[1] = (bf16)a[1]; v[2] = (bf16)a[2]; v[3] = (bf16)a[3];
    v[4] = (bf16)b[0]; v[5] = (bf16)b[1]; v[6] = (bf16)b[2]; v[7] = (bf16)b[3];
    return v;
}

// ---------------- prep 1: x fp32 -> bf16 ----------------
__global__ __launch_bounds__(256)
void xcvt(const float* __restrict__ x, bf16* __restrict__ xb) {
    const size_t i = ((size_t)blockIdx.x * 256 + threadIdx.x) * 8;
    f32x4 a = *(const f32x4*)(x + i);
    f32x4 b = *(const f32x4*)(x + i + 4);
    *(bf16x8*)(xb + i) = cvt8(a, b);
}

// ---------------- prep 2: w[i][n'] fp32 -> wt[n'][i] bf16 ----------------
__global__ __launch_bounds__(256)
void wtrans(const float* __restrict__ w1, const float* __restrict__ w2,
            bf16* __restrict__ w1t, bf16* __restrict__ w2t) {
    __shared__ float s[64][65];
    const int t  = threadIdx.x;
    const int lr = t >> 4;      // 0..15
    const int lq = t & 15;      // 0..15
    const int n0 = blockIdx.x * 64;
    const int i0 = blockIdx.y * 64;
    const float* src = blockIdx.z ? w2 : w1;
    bf16*        dst = blockIdx.z ? w2t : w1t;
#pragma unroll
    for (int r = 0; r < 4; ++r) {
        const int il = lr + 16 * r;
        f32x4 v = *(const f32x4*)(src + (size_t)(i0 + il) * NP_ + n0 + lq * 4);
        s[il][lq * 4 + 0] = v[0]; s[il][lq * 4 + 1] = v[1];
        s[il][lq * 4 + 2] = v[2]; s[il][lq * 4 + 3] = v[3];
    }
    __syncthreads();
#pragma unroll
    for (int r = 0; r < 4; ++r) {
        const int nl = lr + 16 * r;
        bf16x4 o;
        o[0] = (bf16)s[lq * 4 + 0][nl]; o[1] = (bf16)s[lq * 4 + 1][nl];
        o[2] = (bf16)s[lq * 4 + 2][nl]; o[3] = (bf16)s[lq * 4 + 3][nl];
        *(bf16x4*)(dst + (size_t)(n0 + nl) * DIN_ + i0 + lq * 4) = o;
    }
}

// ---------------- main: 256x128 tile, 16 waves, ring-of-4 ----------------
// 64 K-halves of 32 k; ring of 4 LDS regions (32KB):
//   region r = h&3: [A 256x32k 16KB][B1 128x32k 8KB][B2 128x32k 8KB]
// rows 64B; 16B slots pre-swizzled: phys slot p of row r holds slot p^((r>>1)&3).
// 16 waves (4m x 4n), wave tile 64(m) x 32(n') x dual: acc 16 f32x4 = 64 VGPR.
// Per phase h: vmcnt(4) [S(h) landed; S(h+1),S(h+2) in flight]; barrier;
// STG(h+3) [2 loads/thread]; 8 ds_read_b128 + 16 MFMA (compiler-counted lgkm).
__global__ __launch_bounds__(1024, 1)
void mix2_gemm16w(const bf16* __restrict__ xb, const bf16* __restrict__ w1t,
                  const bf16* __restrict__ w2t, const float* __restrict__ b1,
                  const float* __restrict__ b2, float* __restrict__ out)
{
    __shared__ alignas(16) char lds[131072];

    const int tid  = threadIdx.x;
    const int lane = tid & 63;
    const int wid  = tid >> 6;     // 0..15
    const int wm   = wid >> 2;     // 0..3  (64-row slab)
    const int wn   = wid & 3;      // 0..3  (32-col slab)
    const int lk   = lane & 15;
    const int lg   = lane >> 4;

    const int nwg = gridDim.x;     // 2048
    const int bid = (blockIdx.x & 7) * (nwg >> 3) + (blockIdx.x >> 3);
    const int mt  = bid & 7;       // 8 m-tiles of 256
    const int nt  = bid >> 3;      // 256 n-panels of 128

    // staging: A chunk per thread (rows 0..255); B chunk per thread (B1 if tid<512 else B2)
    const int arow = tid >> 2;
    const int aswz = ((tid & 3) ^ ((arow >> 1) & 3)) * 8;
    const int tb   = tid & 511;
    const int brow = tb >> 2;
    const int bswz = ((tb & 3) ^ ((brow >> 1) & 3)) * 8;
    const bf16* gA = xb + (size_t)(mt * 256 + arow) * DIN_ + aswz;
    const bf16* gB = (tid < 512 ? w1t : w2t) + (size_t)(nt * 128 + brow) * DIN_ + bswz;
    const int adst = arow * 64 + (tid & 3) * 16;                       // == tid*16
    const int bdst = 16384 + (tid >= 512 ? 8192 : 0) + tb * 16;

    // fragment read offsets (bytes within a region)
    const int kswz = (lg ^ ((lk >> 1) & 3)) * 16;
    int aoff[4], boff[2];
#pragma unroll
    for (int fm = 0; fm < 4; ++fm) aoff[fm] = (wm * 64 + fm * 16 + lk) * 64 + kswz;
#pragma unroll
    for (int fn = 0; fn < 2; ++fn) boff[fn] = 16384 + (wn * 32 + fn * 16 + lk) * 64 + kswz;

    f32x4 acc1[4][2], acc2[4][2];
#pragma unroll
    for (int i = 0; i < 4; ++i)
#pragma unroll
        for (int j = 0; j < 2; ++j) {
            acc1[i][j] = (f32x4){0.f, 0.f, 0.f, 0.f};
            acc2[i][j] = (f32x4){0.f, 0.f, 0.f, 0.f};
        }

    auto STG = [&](int h) {        // 2 gload_lds per thread into region h&3
        char* r = lds + (h & 3) * 32768;
        const int koff = h * 32;
        __builtin_amdgcn_global_load_lds((gco_void*)(gA + koff), (lds_void*)(r + adst), 16, 0, 0);
        __builtin_amdgcn_global_load_lds((gco_void*)(gB + koff), (lds_void*)(r + bdst), 16, 0, 0);
    };

    auto PHASE = [&](int h) {      // 8 ds_read_b128 + 16 MFMA
        const char* r = lds + (h & 3) * 32768;
        bf16x8 a[4], u[2], v[2];
#pragma unroll
        for (int fn = 0; fn < 2; ++fn) {
            u[fn] = *(const bf16x8*)(r + boff[fn]);
            v[fn] = *(const bf16x8*)(r + boff[fn] + 8192);
        }
#pragma unroll
        for (int fm = 0; fm < 4; ++fm) a[fm] = *(const bf16x8*)(r + aoff[fm]);
        __builtin_amdgcn_s_setprio(1);
#pragma unroll
        for (int fm = 0; fm < 4; ++fm)
#pragma unroll
            for (int fn = 0; fn < 2; ++fn) {
                acc1[fm][fn] = __builtin_amdgcn_mfma_f32_16x16x32_bf16(a[fm], u[fn], acc1[fm][fn], 0, 0, 0);
                acc2[fm][fn] = __builtin_amdgcn_mfma_f32_16x16x32_bf16(a[fm], v[fn], acc2[fm][fn], 0, 0, 0);
            }
        __builtin_amdgcn_s_setprio(0);
    };

#define SYNC(W) do { asm volatile("s_waitcnt vmcnt(" #W ")" ::: "memory"); \
    __builtin_amdgcn_s_barrier(); __builtin_amdgcn_sched_barrier(0); } while (0)

    // prologue: stage halves 0,1,2 (6 loads/thread outstanding)
    STG(0); STG(1); STG(2);

    // phases 0..59 (region static under unroll)
#pragma unroll 1
    for (int t = 0; t < 15; ++t) {
        const int h0 = t * 4;
#pragma unroll
        for (int q = 0; q < 4; ++q) {
            SYNC(4);
            STG(h0 + q + 3);
            PHASE(h0 + q);
        }
    }
    // tail: h = 60..63
    SYNC(4); STG(63); PHASE(60);
    SYNC(4);          PHASE(61);
    SYNC(2);          PHASE(62);
    SYNC(0);          PHASE(63);

#undef SYNC

    // ---- epilogue: k-reduce via shfl_xor, cols lane&15 = 16 k's of one o ----
    const int obase = nt * 8 + wn * 2;
#pragma unroll
    for (int fn = 0; fn < 2; ++fn) {
        const int o = obase + fn;
        const float bb1 = b1[(size_t)o * 16 + lk];
        const float bb2 = b2[o];
#pragma unroll
        for (int fm = 0; fm < 4; ++fm) {
#pragma unroll
            for (int j = 0; j < 4; ++j) {
                float g = fmaxf(acc1[fm][fn][j] + bb1, 0.f);
                float p = g * acc2[fm][fn][j];
                p += __shfl_xor(p, 1);
                p += __shfl_xor(p, 2);
                p += __shfl_xor(p, 4);
                p += __shfl_xor(p, 8);
                if (lk == 0) {
                    const int brow2 = mt * 256 + wm * 64 + fm * 16 + lg * 4 + j;
                    out[(size_t)brow2 * DOUT_ + o] = p + bb2;
                }
            }
        }
    }
}

// ---------------- fallback: round-1 kernel (verified passing) ----------------
__global__ __launch_bounds__(512)
void mix2_fused_direct(const float* __restrict__ x, const float* __restrict__ w1,
                       const float* __restrict__ b1, const float* __restrict__ w2,
                       const float* __restrict__ b2, float* __restrict__ out)
{
    __shared__ alignas(16) char lds[2 * 49152];

    const int tid  = threadIdx.x;
    const int lane = tid & 63;
    const int wid  = tid >> 6;
    const int wm   = wid >> 2;
    const int wn   = wid & 3;

    const int nwg = gridDim.x;
    const int bid = (blockIdx.x & 7) * (nwg >> 3) + (blockIdx.x >> 3);
    const int mt  = bid & 15;
    const int nt  = bid >> 4;

    const int lk  = lane & 15;
    const int lg  = lane >> 4;
    const int swz = (lane & 7) << 4;

    const int a_row  = tid >> 3;
    const int a_col8 = tid & 7;
    const int b_ib = ((tid >> 5) & 15) << 2;
    const int b_nb = (tid & 31) << 2;

    const float* pa  = x  + (size_t)(mt * 128 + a_row) * DIN_ + a_col8 * 8;
    const float* pb1 = w1 + (size_t)b_ib * NP_ + (size_t)nt * 128 + b_nb;
    const float* pb2 = w2 + (size_t)b_ib * NP_ + (size_t)nt * 128 + b_nb;

    const int aswz   = (a_col8 * 16) ^ ((a_row & 7) << 4);
    const int aoffw0 = a_row * 128 + aswz;
    const int aoffw1 = (a_row + 64) * 128 + aswz;

    int aoff[4], boff1[2], boff2[2];
#pragma unroll
    for (int fm = 0; fm < 4; ++fm) aoff[fm] = (wm * 64 + fm * 16 + lk) * 128;
#pragma unroll
    for (int fn = 0; fn < 2; ++fn) {
        const int n = wn * 32 + fn * 16 + lk;
        boff1[fn] = 16384 + n * 128;
        boff2[fn] = 32768 + n * 128;
    }
    const int kp0 = (lg * 16) ^ swz;
    const int kp1 = (64 + lg * 16) ^ swz;

    f32x4 acc1[4][2], acc2[4][2];
#pragma unroll
    for (int i = 0; i < 4; ++i)
#pragma unroll
        for (int j = 0; j < 2; ++j) {
            acc1[i][j] = (f32x4){0.f, 0.f, 0.f, 0.f};
            acc2[i][j] = (f32x4){0.f, 0.f, 0.f, 0.f};
        }

    f32x4 rA[4], rB1[4], rB2[4];

    auto LOAD = [&](int kt) {
        const float* a0 = pa + kt * 64;
        rA[0] = *(const f32x4*)(a0);
        rA[1] = *(const f32x4*)(a0 + 4);
        rA[2] = *(const f32x4*)(a0 + (size_t)64 * DIN_);
        rA[3] = *(const f32x4*)(a0 + (size_t)64 * DIN_ + 4);
        const float* q1 = pb1 + (size_t)kt * 64 * NP_;
        const float* q2 = pb2 + (size_t)kt * 64 * NP_;
#pragma unroll
        for (int j = 0; j < 4; ++j) {
            rB1[j] = *(const f32x4*)(q1 + (size_t)j * NP_);
            rB2[j] = *(const f32x4*)(q2 + (size_t)j * NP_);
        }
    };

    auto STORE = [&](char* s) {
        *(bf16x8*)(s + aoffw0) = cvt8(rA[0], rA[1]);
        *(bf16x8*)(s + aoffw1) = cvt8(rA[2], rA[3]);
        char* s1 = s + 16384;
        char* s2 = s + 32768;
#pragma unroll
        for (int c = 0; c < 4; ++c) {
            const int n   = b_nb + c;
            const int off = n * 128 + ((b_ib * 2) ^ ((n & 7) << 4));
            bf16x4 v1, v2;
            v1[0] = (bf16)rB1[0][c]; v1[1] = (bf16)rB1[1][c];
            v1[2] = (bf16)rB1[2][c]; v1[3] = (bf16)rB1[3][c];
            v2[0] = (bf16)rB2[0][c]; v2[1] = (bf16)rB2[1][c];
            v2[2] = (bf16)rB2[2][c]; v2[3] = (bf16)rB2[3][c];
            *(bf16x4*)(s1 + off) = v1;
            *(bf16x4*)(s2 + off) = v2;
        }
    };

    auto COMPUTE = [&](const char* s) {
#pragma unroll
        for (int kb = 0; kb < 2; ++kb) {
            const int kp = kb ? kp1 : kp0;
            bf16x8 a[4], u[2], v[2];
#pragma unroll
            for (int fm = 0; fm < 4; ++fm) a[fm] = *(const bf16x8*)(s + aoff[fm] + kp);
#pragma unroll
            for (int fn = 0; fn < 2; ++fn) u[fn] = *(const bf16x8*)(s + boff1[fn] + kp);
#pragma unroll
            for (int fn = 0; fn < 2; ++fn) v[fn] = *(const bf16x8*)(s + boff2[fn] + kp);
#pragma unroll
            for (int fm = 0; fm < 4; ++fm)
#pragma unroll
                for (int fn = 0; fn < 2; ++fn) {
                    acc1[fm][fn] = __builtin_amdgcn_mfma_f32_16x16x32_bf16(a[fm], u[fn], acc1[fm][fn], 0, 0, 0);
                    acc2[fm][fn] = __builtin_amdgcn_mfma_f32_16x16x32_bf16(a[fm], v[fn], acc2[fm][fn], 0, 0, 0);
                }
        }
    };

    char* buf0 = lds;
    char* buf1 = lds + 49152;

    LOAD(0);
    STORE(buf0);
    __syncthreads();

    for (int kt = 0; kt < 32; ++kt) {
        if (kt + 1 < 32) LOAD(kt + 1);
        COMPUTE((kt & 1) ? buf1 : buf0);
        if (kt + 1 < 32) {
            STORE((kt & 1) ? buf0 : buf1);
            __syncthreads();
        }
    }

    const int obase = nt * 8 + wn * 2;
#pragma unroll
    for (int fn = 0; fn < 2; ++fn) {
        const int o = obase + fn;
        const float bb1 = b1[(size_t)o * 16 + lk];
        const float bb2 = b2[o];
#pragma unroll
        for (int fm = 0; fm < 4; ++fm) {
#pragma unroll
            for (int j = 0; j < 4; ++j) {
                float g = fmaxf(acc1[fm][fn][j] + bb1, 0.f);
                float p = g * acc2[fm][fn][j];
                p += __shfl_xor(p, 1);
                p += __shfl_xor(p, 2);
                p += __shfl_xor(p, 4);
                p += __shfl_xor(p, 8);
                if (lk == 0) {
                    const int brow = mt * 128 + wm * 64 + fm * 16 + lg * 4 + j;
                    out[(size_t)brow * DOUT_ + o] = p + bb2;
                }
            }
        }
    }
}

extern "C" void kernel_launch(void* const* d_in, const int* in_sizes, int n_in,
                              void* d_out, int out_size, void* d_ws, size_t ws_size,
                              hipStream_t stream) {
    (void)in_sizes; (void)n_in; (void)out_size;
    const float* x  = (const float*)d_in[0];
    const float* w1 = (const float*)d_in[1];
    const float* b1 = (const float*)d_in[2];
    const float* w2 = (const float*)d_in[3];
    const float* b2 = (const float*)d_in[4];
    float* out = (float*)d_out;

    const size_t XB   = (size_t)DIN_ * DIN_ * 2;            // 8 MB   (x bf16)
    const size_t WT   = (size_t)NP_ * DIN_ * 2;             // 128 MB (each wt)
    const size_t NEED = XB + 2 * WT;                        // 264 MB

    if (ws_size >= NEED) {
        bf16* xb  = (bf16*)d_ws;
        bf16* w1t = (bf16*)((char*)d_ws + XB);
        bf16* w2t = (bf16*)((char*)d_ws + XB + WT);
        hipLaunchKernelGGL(xcvt,   dim3(2048),        dim3(256),  0, stream, x, xb);
        hipLaunchKernelGGL(wtrans, dim3(512, 32, 2),  dim3(256),  0, stream, w1, w2, w1t, w2t);
        hipLaunchKernelGGL(mix2_gemm16w, dim3(2048),  dim3(1024), 0, stream, xb, w1t, w2t, b1, b2, out);
    } else {
        hipLaunchKernelGGL(mix2_fused_direct, dim3(4096), dim3(512), 0, stream, x, w1, b1, w2, b2, out);
    }
}

// Round 12
// 634.322 us; speedup vs baseline: 2.2362x; 1.0133x over previous
//
#include <hip/hip_runtime.h>
#include <hip/hip_bf16.h>

// Mix2Layer: out[b,o] = sum_k relu(sum_i x[b,i]*w1[i,o,k] + b1[o,k]) * (sum_i x[b,i]*w2[i,o,k]) + b2[o]
// B=2048, DIN=2048, DOUT=2048, K=16.  N' = o*16+k (w row-major [DIN][32768]).
//
// Fast path (needs ws >= 264MB):
//   1) xcvt:   x fp32 -> bf16                  (8 MB)
//   2) wtrans: w[i][n'] fp32 -> wt[n'][i] bf16 (128 MB each)
//   3) mix2_gemm2b: 256x128 tile, BK=64, double-buffer (2x64KB), 16 waves
//      (4 waves/SIMD — R11's proven TLP), ONE barrier + one (cheap) vmcnt(0)
//      per 64-k phase; 16 ds_reads + 32 MFMA per wave per phase.
// Fallback: round-1 in-kernel-transpose kernel (verified passing).

typedef __bf16 bf16;
typedef bf16 bf16x8 __attribute__((ext_vector_type(8)));
typedef bf16 bf16x4 __attribute__((ext_vector_type(4)));
typedef float f32x4 __attribute__((ext_vector_type(4)));

typedef __attribute__((address_space(1))) const void gco_void;
typedef __attribute__((address_space(3))) void lds_void;

#define DIN_   2048
#define DOUT_  2048
#define NP_    32768   // DOUT*K

__device__ __forceinline__ bf16x8 cvt8(f32x4 a, f32x4 b) {
    bf16x8 v;
    v[0] = (bf16)a[0]; v[1] = (bf16)a[1]; v[2] = (bf16)a[2]; v[3] = (bf16)a[3];
    v[4] = (bf16)b[0]; v[5] = (bf16)b[1]; v[6] = (bf16)b[2]; v[7] = (bf16)b[3];
    return v;
}

// ---------------- prep 1: x fp32 -> bf16 ----------------
__global__ __launch_bounds__(256)
void xcvt(const float* __restrict__ x, bf16* __restrict__ xb) {
    const size_t i = ((size_t)blockIdx.x * 256 + threadIdx.x) * 8;
    f32x4 a = *(const f32x4*)(x + i);
    f32x4 b = *(const f32x4*)(x + i + 4);
    *(bf16x8*)(xb + i) = cvt8(a, b);
}

// ---------------- prep 2: w[i][n'] fp32 -> wt[n'][i] bf16 ----------------
__global__ __launch_bounds__(256)
void wtrans(const float* __restrict__ w1, const float* __restrict__ w2,
            bf16* __restrict__ w1t, bf16* __restrict__ w2t) {
    __shared__ float s[64][65];
    const int t  = threadIdx.x;
    const int lr = t >> 4;      // 0..15
    const int lq = t & 15;      // 0..15
    const int n0 = blockIdx.x * 64;
    const int i0 = blockIdx.y * 64;
    const float* src = blockIdx.z ? w2 : w1;
    bf16*        dst = blockIdx.z ? w2t : w1t;
#pragma unroll
    for (int r = 0; r < 4; ++r) {
        const int il = lr + 16 * r;
        f32x4 v = *(const f32x4*)(src + (size_t)(i0 + il) * NP_ + n0 + lq * 4);
        s[il][lq * 4 + 0] = v[0]; s[il][lq * 4 + 1] = v[1];
        s[il][lq * 4 + 2] = v[2]; s[il][lq * 4 + 3] = v[3];
    }
    __syncthreads();
#pragma unroll
    for (int r = 0; r < 4; ++r) {
        const int nl = lr + 16 * r;
        bf16x4 o;
        o[0] = (bf16)s[lq * 4 + 0][nl]; o[1] = (bf16)s[lq * 4 + 1][nl];
        o[2] = (bf16)s[lq * 4 + 2][nl]; o[3] = (bf16)s[lq * 4 + 3][nl];
        *(bf16x4*)(dst + (size_t)(n0 + nl) * DIN_ + i0 + lq * 4) = o;
    }
}

// ---------------- main: 256x128 tile, BK=64, double-buffer, 16 waves ----------------
// 32 K-tiles of 64 k; 2 LDS buffers (64KB):
//   buf = t&1: [A 256x64k 32KB][B1 128x64k 16KB][B2 128x64k 16KB]
// rows 128B = 8 slots of 16B; phys slot p of row r holds data slot p^(r&7)
// (pre-swizzled global source; fragment reads apply the same XOR -> 2 lanes/bank).
// Per phase t: vmcnt(0) [S(t) landed; issued a full phase ago -> ~free]; barrier;
// STG(t+1) [4 loads/thread]; 16 ds_read_b128 + 32 MFMA (compiler-counted lgkm).
__global__ __launch_bounds__(1024, 1)
void mix2_gemm2b(const bf16* __restrict__ xb, const bf16* __restrict__ w1t,
                 const bf16* __restrict__ w2t, const float* __restrict__ b1,
                 const float* __restrict__ b2, float* __restrict__ out)
{
    __shared__ alignas(16) char lds[131072];

    const int tid  = threadIdx.x;
    const int lane = tid & 63;
    const int wid  = tid >> 6;     // 0..15
    const int wm   = wid >> 2;     // 0..3  (64-row slab)
    const int wn   = wid & 3;      // 0..3  (32-col slab)
    const int lk   = lane & 15;
    const int lg   = lane >> 4;

    const int nwg = gridDim.x;     // 2048
    const int bid = (blockIdx.x & 7) * (nwg >> 3) + (blockIdx.x >> 3);
    const int mt  = bid & 7;       // 8 m-tiles of 256
    const int nt  = bid >> 3;      // 256 n-panels of 128

    // staging: chunk c -> row=c>>3, phys slot=c&7 holds data slot (c&7)^(row&7)
    const int srow = tid >> 3;                 // 0..127
    const int sswz = ((tid & 7) ^ (srow & 7)) * 8;
    const bf16* gA0 = xb  + (size_t)(mt * 256 + srow) * DIN_ + sswz;  // rows 0..127
    const bf16* gA1 = gA0 + (size_t)128 * DIN_;                        // rows 128..255
    const bf16* gB1 = w1t + (size_t)(nt * 128 + srow) * DIN_ + sswz;
    const bf16* gB2 = w2t + (size_t)(nt * 128 + srow) * DIN_ + sswz;

    // fragment read offsets (bytes within a buffer), per k-half h2:
    // byte = row*128 + ((h2*4+lg) ^ (row&7))*16 ; row&7 == lk&7 for all frags
    int aoff[4][2], boff[2][2];
#pragma unroll
    for (int fm = 0; fm < 4; ++fm)
#pragma unroll
        for (int h2 = 0; h2 < 2; ++h2) {
            const int row = wm * 64 + fm * 16 + lk;
            aoff[fm][h2] = row * 128 + (((h2 * 4 + lg) ^ (row & 7)) << 4);
        }
#pragma unroll
    for (int fn = 0; fn < 2; ++fn)
#pragma unroll
        for (int h2 = 0; h2 < 2; ++h2) {
            const int row = wn * 32 + fn * 16 + lk;
            boff[fn][h2] = 32768 + row * 128 + (((h2 * 4 + lg) ^ (row & 7)) << 4);
        }

    f32x4 acc1[4][2], acc2[4][2];
#pragma unroll
    for (int i = 0; i < 4; ++i)
#pragma unroll
        for (int j = 0; j < 2; ++j) {
            acc1[i][j] = (f32x4){0.f, 0.f, 0.f, 0.f};
            acc2[i][j] = (f32x4){0.f, 0.f, 0.f, 0.f};
        }

    auto STG = [&](int t) {        // 4 gload_lds per thread into buf t&1
        char* r = lds + (t & 1) * 65536;
        const int koff = t * 64;
        __builtin_amdgcn_global_load_lds((gco_void*)(gA0 + koff), (lds_void*)(r + tid * 16),          16, 0, 0);
        __builtin_amdgcn_global_load_lds((gco_void*)(gA1 + koff), (lds_void*)(r + 16384 + tid * 16),  16, 0, 0);
        __builtin_amdgcn_global_load_lds((gco_void*)(gB1 + koff), (lds_void*)(r + 32768 + tid * 16),  16, 0, 0);
        __builtin_amdgcn_global_load_lds((gco_void*)(gB2 + koff), (lds_void*)(r + 49152 + tid * 16),  16, 0, 0);
    };

    auto COMPUTE = [&](const char* r) {   // 16 ds_read_b128 + 32 MFMA (2 k-halves)
#pragma unroll
        for (int h2 = 0; h2 < 2; ++h2) {
            bf16x8 a[4], u[2], v[2];
#pragma unroll
            for (int fn = 0; fn < 2; ++fn) {
                u[fn] = *(const bf16x8*)(r + boff[fn][h2]);
                v[fn] = *(const bf16x8*)(r + boff[fn][h2] + 16384);
            }
#pragma unroll
            for (int fm = 0; fm < 4; ++fm) a[fm] = *(const bf16x8*)(r + aoff[fm][h2]);
            __builtin_amdgcn_s_setprio(1);
#pragma unroll
            for (int fm = 0; fm < 4; ++fm)
#pragma unroll
                for (int fn = 0; fn < 2; ++fn) {
                    acc1[fm][fn] = __builtin_amdgcn_mfma_f32_16x16x32_bf16(a[fm], u[fn], acc1[fm][fn], 0, 0, 0);
                    acc2[fm][fn] = __builtin_amdgcn_mfma_f32_16x16x32_bf16(a[fm], v[fn], acc2[fm][fn], 0, 0, 0);
                }
            __builtin_amdgcn_s_setprio(0);
        }
    };

#define SYNC() do { asm volatile("s_waitcnt vmcnt(0)" ::: "memory"); \
    __builtin_amdgcn_s_barrier(); __builtin_amdgcn_sched_barrier(0); } while (0)

    const char* buf0 = lds;
    const char* buf1 = lds + 65536;

    // prologue: stage tile 0
    STG(0);

    // phases 0..29 in pairs; each phase stages the next tile
#pragma unroll 1
    for (int tt = 0; tt < 15; ++tt) {
        const int t = tt * 2;
        SYNC(); STG(t + 1); COMPUTE(buf0);
        SYNC(); STG(t + 2); COMPUTE(buf1);
    }
    // t = 30 (stage S(31)), t = 31
    SYNC(); STG(31); COMPUTE(buf0);
    SYNC();          COMPUTE(buf1);

#undef SYNC

    // ---- epilogue: k-reduce via shfl_xor, cols lane&15 = 16 k's of one o ----
    const int obase = nt * 8 + wn * 2;
#pragma unroll
    for (int fn = 0; fn < 2; ++fn) {
        const int o = obase + fn;
        const float bb1 = b1[(size_t)o * 16 + lk];
        const float bb2 = b2[o];
#pragma unroll
        for (int fm = 0; fm < 4; ++fm) {
#pragma unroll
            for (int j = 0; j < 4; ++j) {
                float g = fmaxf(acc1[fm][fn][j] + bb1, 0.f);
                float p = g * acc2[fm][fn][j];
                p += __shfl_xor(p, 1);
                p += __shfl_xor(p, 2);
                p += __shfl_xor(p, 4);
                p += __shfl_xor(p, 8);
                if (lk == 0) {
                    const int brow = mt * 256 + wm * 64 + fm * 16 + lg * 4 + j;
                    out[(size_t)brow * DOUT_ + o] = p + bb2;
                }
            }
        }
    }
}

// ---------------- fallback: round-1 kernel (verified passing) ----------------
__global__ __launch_bounds__(512)
void mix2_fused_direct(const float* __restrict__ x, const float* __restrict__ w1,
                       const float* __restrict__ b1, const float* __restrict__ w2,
                       const float* __restrict__ b2, float* __restrict__ out)
{
    __shared__ alignas(16) char lds[2 * 49152];

    const int tid  = threadIdx.x;
    const int lane = tid & 63;
    const int wid  = tid >> 6;
    const int wm   = wid >> 2;
    const int wn   = wid & 3;

    const int nwg = gridDim.x;
    const int bid = (blockIdx.x & 7) * (nwg >> 3) + (blockIdx.x >> 3);
    const int mt  = bid & 15;
    const int nt  = bid >> 4;

    const int lk  = lane & 15;
    const int lg  = lane >> 4;
    const int swz = (lane & 7) << 4;

    const int a_row  = tid >> 3;
    const int a_col8 = tid & 7;
    const int b_ib = ((tid >> 5) & 15) << 2;
    const int b_nb = (tid & 31) << 2;

    const float* pa  = x  + (size_t)(mt * 128 + a_row) * DIN_ + a_col8 * 8;
    const float* pb1 = w1 + (size_t)b_ib * NP_ + (size_t)nt * 128 + b_nb;
    const float* pb2 = w2 + (size_t)b_ib * NP_ + (size_t)nt * 128 + b_nb;

    const int aswz   = (a_col8 * 16) ^ ((a_row & 7) << 4);
    const int aoffw0 = a_row * 128 + aswz;
    const int aoffw1 = (a_row + 64) * 128 + aswz;

    int aoff[4], boff1[2], boff2[2];
#pragma unroll
    for (int fm = 0; fm < 4; ++fm) aoff[fm] = (wm * 64 + fm * 16 + lk) * 128;
#pragma unroll
    for (int fn = 0; fn < 2; ++fn) {
        const int n = wn * 32 + fn * 16 + lk;
        boff1[fn] = 16384 + n * 128;
        boff2[fn] = 32768 + n * 128;
    }
    const int kp0 = (lg * 16) ^ swz;
    const int kp1 = (64 + lg * 16) ^ swz;

    f32x4 acc1[4][2], acc2[4][2];
#pragma unroll
    for (int i = 0; i < 4; ++i)
#pragma unroll
        for (int j = 0; j < 2; ++j) {
            acc1[i][j] = (f32x4){0.f, 0.f, 0.f, 0.f};
            acc2[i][j] = (f32x4){0.f, 0.f, 0.f, 0.f};
        }

    f32x4 rA[4], rB1[4], rB2[4];

    auto LOAD = [&](int kt) {
        const float* a0 = pa + kt * 64;
        rA[0] = *(const f32x4*)(a0);
        rA[1] = *(const f32x4*)(a0 + 4);
        rA[2] = *(const f32x4*)(a0 + (size_t)64 * DIN_);
        rA[3] = *(const f32x4*)(a0 + (size_t)64 * DIN_ + 4);
        const float* q1 = pb1 + (size_t)kt * 64 * NP_;
        const float* q2 = pb2 + (size_t)kt * 64 * NP_;
#pragma unroll
        for (int j = 0; j < 4; ++j) {
            rB1[j] = *(const f32x4*)(q1 + (size_t)j * NP_);
            rB2[j] = *(const f32x4*)(q2 + (size_t)j * NP_);
        }
    };

    auto STORE = [&](char* s) {
        *(bf16x8*)(s + aoffw0) = cvt8(rA[0], rA[1]);
        *(bf16x8*)(s + aoffw1) = cvt8(rA[2], rA[3]);
        char* s1 = s + 16384;
        char* s2 = s + 32768;
#pragma unroll
        for (int c = 0; c < 4; ++c) {
            const int n   = b_nb + c;
            const int off = n * 128 + ((b_ib * 2) ^ ((n & 7) << 4));
            bf16x4 v1, v2;
            v1[0] = (bf16)rB1[0][c]; v1[1] = (bf16)rB1[1][c];
            v1[2] = (bf16)rB1[2][c]; v1[3] = (bf16)rB1[3][c];
            v2[0] = (bf16)rB2[0][c]; v2[1] = (bf16)rB2[1][c];
            v2[2] = (bf16)rB2[2][c]; v2[3] = (bf16)rB2[3][c];
            *(bf16x4*)(s1 + off) = v1;
            *(bf16x4*)(s2 + off) = v2;
        }
    };

    auto COMPUTE = [&](const char* s) {
#pragma unroll
        for (int kb = 0; kb < 2; ++kb) {
            const int kp = kb ? kp1 : kp0;
            bf16x8 a[4], u[2], v[2];
#pragma unroll
            for (int fm = 0; fm < 4; ++fm) a[fm] = *(const bf16x8*)(s + aoff[fm] + kp);
#pragma unroll
            for (int fn = 0; fn < 2; ++fn) u[fn] = *(const bf16x8*)(s + boff1[fn] + kp);
#pragma unroll
            for (int fn = 0; fn < 2; ++fn) v[fn] = *(const bf16x8*)(s + boff2[fn] + kp);
#pragma unroll
            for (int fm = 0; fm < 4; ++fm)
#pragma unroll
                for (int fn = 0; fn < 2; ++fn) {
                    acc1[fm][fn] = __builtin_amdgcn_mfma_f32_16x16x32_bf16(a[fm], u[fn], acc1[fm][fn], 0, 0, 0);
                    acc2[fm][fn] = __builtin_amdgcn_mfma_f32_16x16x32_bf16(a[fm], v[fn], acc2[fm][fn], 0, 0, 0);
                }
        }
    };

    char* buf0 = lds;
    char* buf1 = lds + 49152;

    LOAD(0);
    STORE(buf0);
    __syncthreads();

    for (int kt = 0; kt < 32; ++kt) {
        if (kt + 1 < 32) LOAD(kt + 1);
        COMPUTE((kt & 1) ? buf1 : buf0);
        if (kt + 1 < 32) {
            STORE((kt & 1) ? buf0 : buf1);
            __syncthreads();
        }
    }

    const int obase = nt * 8 + wn * 2;
#pragma unroll
    for (int fn = 0; fn < 2; ++fn) {
        const int o = obase + fn;
        const float bb1 = b1[(size_t)o * 16 + lk];
        const float bb2 = b2[o];
#pragma unroll
        for (int fm = 0; fm < 4; ++fm) {
#pragma unroll
            for (int j = 0; j < 4; ++j) {
                float g = fmaxf(acc1[fm][fn][j] + bb1, 0.f);
                float p = g * acc2[fm][fn][j];
                p += __shfl_xor(p, 1);
                p += __shfl_xor(p, 2);
                p += __shfl_xor(p, 4);
                p += __shfl_xor(p, 8);
                if (lk == 0) {
                    const int brow = mt * 128 + wm * 64 + fm * 16 + lg * 4 + j;
                    out[(size_t)brow * DOUT_ + o] = p + bb2;
                }
            }
        }
    }
}

extern "C" void kernel_launch(void* const* d_in, const int* in_sizes, int n_in,
                              void* d_out, int out_size, void* d_ws, size_t ws_size,
                              hipStream_t stream) {
    (void)in_sizes; (void)n_in; (void)out_size;
    const float* x  = (const float*)d_in[0];
    const float* w1 = (const float*)d_in[1];
    const float* b1 = (const float*)d_in[2];
    const float* w2 = (const float*)d_in[3];
    const float* b2 = (const float*)d_in[4];
    float* out = (float*)d_out;

    const size_t XB   = (size_t)DIN_ * DIN_ * 2;            // 8 MB   (x bf16)
    const size_t WT   = (size_t)NP_ * DIN_ * 2;             // 128 MB (each wt)
    const size_t NEED = XB + 2 * WT;                        // 264 MB

    if (ws_size >= NEED) {
        bf16* xb  = (bf16*)d_ws;
        bf16* w1t = (bf16*)((char*)d_ws + XB);
        bf16* w2t = (bf16*)((char*)d_ws + XB + WT);
        hipLaunchKernelGGL(xcvt,   dim3(2048),       dim3(256),  0, stream, x, xb);
        hipLaunchKernelGGL(wtrans, dim3(512, 32, 2), dim3(256),  0, stream, w1, w2, w1t, w2t);
        hipLaunchKernelGGL(mix2_gemm2b, dim3(2048),  dim3(1024), 0, stream, xb, w1t, w2t, b1, b2, out);
    } else {
        hipLaunchKernelGGL(mix2_fused_direct, dim3(4096), dim3(512), 0, stream, x, w1, b1, w2, b2, out);
    }
}